// Round 1
// baseline (1650.995 us; speedup 1.0000x reference)
//
#include <hip/hip_runtime.h>
#include <math.h>

typedef long long ll;

// ---------------------------------------------------------------------------
// Generic strided fp32 GEMM: C[b][i][j] = alpha * sum_k A[i,k]*B[k,j] + beta*Cin
// A accessed as A[b*aB + i*aI + k*aK], B as B[b*bB + k*bK + j*bJ],
// C row-major with row stride cI (contiguous j). 64x64 tile, 256 threads, 4x4 acc.
// ---------------------------------------------------------------------------
__global__ __launch_bounds__(256) void gemm_k(
    const float* __restrict__ A, ll aB, ll aI, ll aK,
    const float* __restrict__ B, ll bB, ll bK, ll bJ,
    const float* __restrict__ Cin, ll ciB, float beta,
    float* __restrict__ C, ll cB, ll cI,
    int M, int N, int K, float alpha)
{
    int b = blockIdx.z;
    A += (ll)b * aB;
    B += (ll)b * bB;
    C += (ll)b * cB;
    if (Cin) Cin += (ll)b * ciB;
    int i0 = blockIdx.y * 64, j0 = blockIdx.x * 64;
    __shared__ float As[16][65], Bs[16][65];
    int tid = threadIdx.x;
    int tx = tid & 15, ty = tid >> 4;
    float acc[4][4] = {};

    for (int k0 = 0; k0 < K; k0 += 16) {
        // --- load A tile (16 K x 64 I) ---
        if (aK == 1) {
            // contiguous in k: quarter-wave reads 16 consecutive floats
            for (int t = tid; t < 1024; t += 256) {
                int ii = t >> 4, kk = t & 15;
                int gi = i0 + ii, gk = k0 + kk;
                As[kk][ii] = (gi < M && gk < K) ? A[(ll)gi * aI + (ll)gk] : 0.f;
            }
        } else {
            // contiguous in i (aI typically 1): lanes along ii
            for (int t = tid; t < 1024; t += 256) {
                int kk = t >> 6, ii = t & 63;
                int gi = i0 + ii, gk = k0 + kk;
                As[kk][ii] = (gi < M && gk < K) ? A[(ll)gi * aI + (ll)gk * aK] : 0.f;
            }
        }
        // --- load B tile (16 K x 64 J) ---
        if (bK == 1) {
            for (int t = tid; t < 1024; t += 256) {
                int jj = t >> 4, kk = t & 15;
                int gj = j0 + jj, gk = k0 + kk;
                Bs[kk][jj] = (gj < N && gk < K) ? B[(ll)gk + (ll)gj * bJ] : 0.f;
            }
        } else {
            for (int t = tid; t < 1024; t += 256) {
                int kk = t >> 6, jj = t & 63;
                int gj = j0 + jj, gk = k0 + kk;
                Bs[kk][jj] = (gj < N && gk < K) ? B[(ll)gk * bK + (ll)gj * bJ] : 0.f;
            }
        }
        __syncthreads();
        #pragma unroll
        for (int kk = 0; kk < 16; ++kk) {
            float a[4], bv[4];
            #pragma unroll
            for (int m = 0; m < 4; ++m) a[m] = As[kk][ty + m * 16];
            #pragma unroll
            for (int n = 0; n < 4; ++n) bv[n] = Bs[kk][tx + n * 16];
            #pragma unroll
            for (int m = 0; m < 4; ++m)
                #pragma unroll
                for (int n = 0; n < 4; ++n)
                    acc[m][n] = fmaf(a[m], bv[n], acc[m][n]);
        }
        __syncthreads();
    }

    #pragma unroll
    for (int m = 0; m < 4; ++m) {
        int gi = i0 + ty + m * 16;
        if (gi >= M) continue;
        #pragma unroll
        for (int n = 0; n < 4; ++n) {
            int gj = j0 + tx + n * 16;
            if (gj >= N) continue;
            float v = alpha * acc[m][n];
            if (Cin) v = fmaf(beta, Cin[(ll)gi * cI + gj], v);
            C[(ll)gi * cI + gj] = v;
        }
    }
}

// W = blockdiag(I64, emb(128x128), I128)  -> (320 x 320)
__global__ void build_W_k(const float* __restrict__ emb, float* __restrict__ W)
{
    int idx = blockIdx.x * 256 + threadIdx.x;
    if (idx >= 320 * 320) return;
    int i = idx / 320, j = idx % 320;
    float v = 0.f;
    if (i < 64) v = (i == j) ? 1.f : 0.f;
    else if (i < 192) v = (j >= 64 && j < 192) ? emb[(i - 64) * 128 + (j - 64)] : 0.f;
    else v = (j == i) ? 1.f : 0.f;
    W[idx] = v;
}

// r0[b][c][i] = emb[i-192][c] for i in [192,320), else 0.  (16 x 128 x 320)
__global__ void init_r_k(const float* __restrict__ emb, float* __restrict__ r)
{
    int idx = blockIdx.x * 256 + threadIdx.x;
    if (idx >= 16 * 128 * 320) return;
    int i = idx % 320;
    int c = (idx / 320) % 128;
    r[idx] = (i >= 192) ? emb[(i - 192) * 128 + c] : 0.f;
}

// G[b] += U[b] + U[b]^T + V[b]   (per-batch 320x320)
__global__ void gupd_k(float* __restrict__ G, const float* __restrict__ U,
                       const float* __restrict__ V)
{
    int b = blockIdx.y;
    int idx = blockIdx.x * 256 + threadIdx.x;
    if (idx >= 320 * 320) return;
    int i = idx / 320, j = idx % 320;
    const float* Ub = U + (ll)b * 102400;
    ll o = (ll)b * 102400 + idx;
    G[o] += Ub[idx] + Ub[j * 320 + i] + V[o];
}

// row softmax over 128 categories; one wave (64 lanes) per row
__global__ __launch_bounds__(256) void softmax_k(const float* __restrict__ logits,
                                                 float* __restrict__ pred)
{
    int wave = (blockIdx.x * 256 + threadIdx.x) >> 6;
    int lane = threadIdx.x & 63;
    if (wave >= 16 * 2048) return;
    const float* row = logits + (ll)wave * 128;
    float v0 = row[lane], v1 = row[lane + 64];
    float mx = fmaxf(v0, v1);
    #pragma unroll
    for (int off = 32; off; off >>= 1) mx = fmaxf(mx, __shfl_xor(mx, off));
    float e0 = expf(v0 - mx), e1 = expf(v1 - mx);
    float sm = e0 + e1;
    #pragma unroll
    for (int off = 32; off; off >>= 1) sm += __shfl_xor(sm, off);
    float inv = 1.f / sm;
    float* prow = pred + (ll)wave * 128;
    prow[lane] = e0 * inv;
    prow[lane + 64] = e1 * inv;
}

extern "C" void kernel_launch(void* const* d_in, const int* in_sizes, int n_in,
                              void* d_out, int out_size, void* d_ws, size_t ws_size,
                              hipStream_t stream)
{
    const float* x   = (const float*)d_in[0];  // (16, 320, 2048)
    const float* emb = (const float*)d_in[1];  // (128, 128)
    const float* Wq  = (const float*)d_in[2];  // (3,1,320,320)
    const float* Wk  = (const float*)d_in[3];
    const float* Wv  = (const float*)d_in[4];
    const float* P   = (const float*)d_in[5];

    float* logits = (float*)d_out;                    // (16, 2048, 128)
    float* pred   = logits + (ll)16 * 2048 * 128;     // (16, 2048, 128)

    const ll SZ = 320 * 320;       // 102400
    const ll RS = (ll)128 * 320;   // 40960
    float* ws = (float*)d_ws;
    float* W   = ws;  ws += SZ;
    float* Gx  = ws;  ws += 16 * SZ;
    float* T1  = ws;  ws += 16 * SZ;   // scratch (W*Gx, G*KQ)
    float* G   = ws;  ws += 16 * SZ;
    float* PV  = ws;  ws += 3 * SZ;
    float* KQ  = ws;  ws += 3 * SZ;
    float* Al  = ws;  ws += 48 * SZ;   // A matrices, 3 layers x 16 batches
    float* U   = ws;  ws += 16 * SZ;
    float* V   = ws;  ws += 16 * SZ;
    float* r0  = ws;  ws += 16 * RS;
    float* r1  = ws;  ws += 16 * RS;
    float* LW  = ws;  ws += 16 * RS;

    auto gemm = [&](const float* A, ll aB, ll aI, ll aK,
                    const float* B, ll bB, ll bK, ll bJ,
                    const float* Cin, ll ciB, float beta,
                    float* C, ll cB, ll cI,
                    int M, int N, int K, int batch, float alpha) {
        dim3 g((N + 63) / 64, (M + 63) / 64, batch);
        gemm_k<<<g, 256, 0, stream>>>(A, aB, aI, aK, B, bB, bK, bJ,
                                      Cin, ciB, beta, C, cB, cI, M, N, K, alpha);
    };

    // 1) W = blockdiag(I64, emb, I128)
    build_W_k<<<400, 256, 0, stream>>>(emb, W);

    // 2) Gx[b] = x[:, :2047] @ x[:, :2047]^T   (320x320, K=2047)
    gemm(x, (ll)320 * 2048, 2048, 1,
         x, (ll)320 * 2048, 1, 2048,
         nullptr, 0, 0.f,
         Gx, SZ, 320, 320, 320, 2047, 16, 1.f);

    // 3) G = W @ Gx @ W^T
    gemm(W, 0, 320, 1,  Gx, SZ, 320, 1,  nullptr, 0, 0.f,  T1, SZ, 320, 320, 320, 320, 16, 1.f);
    gemm(T1, SZ, 320, 1,  W, 0, 1, 320,  nullptr, 0, 0.f,  G,  SZ, 320, 320, 320, 320, 16, 1.f);

    // 4) PV_l = P_l @ Wv_l ; KQ_l = Wk_l^T @ Wq_l  (batch over 3 layers)
    gemm(P,  SZ, 320, 1,  Wv, SZ, 320, 1,  nullptr, 0, 0.f,  PV, SZ, 320, 320, 320, 320, 3, 1.f);
    gemm(Wk, SZ, 1, 320,  Wq, SZ, 320, 1,  nullptr, 0, 0.f,  KQ, SZ, 320, 320, 320, 320, 3, 1.f);

    // 5) layer chain: A_l = (1/2047) PV_l @ (G @ KQ_l);  G <- G + U + U^T + U A^T
    for (int l = 0; l < 3; ++l) {
        float* Acur = Al + (ll)l * 16 * SZ;
        gemm(G, SZ, 320, 1,  KQ + (ll)l * SZ, 0, 320, 1,  nullptr, 0, 0.f,
             T1, SZ, 320, 320, 320, 320, 16, 1.f);
        gemm(PV + (ll)l * SZ, 0, 320, 1,  T1, SZ, 320, 1,  nullptr, 0, 0.f,
             Acur, SZ, 320, 320, 320, 320, 16, 1.f / 2047.f);
        if (l < 2) {
            gemm(Acur, SZ, 320, 1,  G, SZ, 320, 1,  nullptr, 0, 0.f,
                 U, SZ, 320, 320, 320, 320, 16, 1.f);
            gemm(U, SZ, 320, 1,  Acur, SZ, 1, 320,  nullptr, 0, 0.f,
                 V, SZ, 320, 320, 320, 320, 16, 1.f);
            gupd_k<<<dim3(400, 16), 256, 0, stream>>>(G, U, V);
        }
    }

    // 6) r = emb_sel; r <- r + r @ A_l for l = 2,1,0;  LW = r @ W
    init_r_k<<<2560, 256, 0, stream>>>(emb, r0);
    float* rc = r0;
    float* rn = r1;
    for (int l = 2; l >= 0; --l) {
        gemm(rc, RS, 320, 1,  Al + (ll)l * 16 * SZ, SZ, 320, 1,
             rc, RS, 1.f,
             rn, RS, 320, 128, 320, 320, 16, 1.f);
        float* t = rc; rc = rn; rn = t;
    }
    gemm(rc, RS, 320, 1,  W, 0, 320, 1,  nullptr, 0, 0.f,
         LW, RS, 320, 128, 320, 320, 16, 1.f);

    // 7) logits[b][n][c] = sum_f x[b][f][n] * LW[b][c][f]
    gemm(x, (ll)320 * 2048, 1, 2048,
         LW, RS, 1, 320,
         nullptr, 0, 0.f,
         logits, (ll)2048 * 128, 128, 2048, 128, 320, 16, 1.f);

    // 8) predictions = softmax(logits, axis=-1)
    softmax_k<<<8192, 256, 0, stream>>>(logits, pred);
}

// Round 2
// 604.671 us; speedup vs baseline: 2.7304x; 2.7304x over previous
//
#include <hip/hip_runtime.h>
#include <math.h>

typedef long long ll;

// ---------------------------------------------------------------------------
// fp32 GEMM v2: C[b](MxN) = alpha*A.B (+Cin) (+Cin^T) (+=C)
// A[b*aB + i*aI + k*aK], B[b*bB + k*bK + j*bJ]. C row-major stride N.
// REQUIRES: M,N multiples of 64; K multiple of 16; either aK==1 or aI==1;
// either bJ==1 or bK==1. 64x64 tile, 256 threads, 4x4 acc via float4 LDS.
// cinMode: 0 none, 1 +Cin[i,j], 2 +Cin[i,j]+Cin[j,i] (needs M==N).
// accum: 1 -> C += v instead of C = v.
// ---------------------------------------------------------------------------
__global__ __launch_bounds__(256) void gemm_k(
    const float* __restrict__ A, ll aB, ll aI, ll aK,
    const float* __restrict__ B, ll bB, ll bK, ll bJ,
    const float* __restrict__ Cin, ll ciB, int cinMode,
    float* __restrict__ C, ll cB, int accum,
    int M, int N, int K, float alpha)
{
    int b = blockIdx.z;
    A += (ll)b * aB;
    B += (ll)b * bB;
    C += (ll)b * cB;
    if (Cin) Cin += (ll)b * ciB;
    int i0 = blockIdx.y * 64, j0 = blockIdx.x * 64;
    __shared__ float As[16][68], Bs[16][68];
    int tid = threadIdx.x;
    int tx = tid & 15, ty = tid >> 4;
    float acc[4][4] = {};

    for (int k0 = 0; k0 < K; k0 += 16) {
        if (aK == 1) {                       // k contiguous: float4 along k, transpose into LDS
            int f = tid >> 2, kq = tid & 3;
            float4 v = *(const float4*)(A + (ll)(i0 + f) * aI + (k0 + kq * 4));
            As[kq * 4 + 0][f] = v.x; As[kq * 4 + 1][f] = v.y;
            As[kq * 4 + 2][f] = v.z; As[kq * 4 + 3][f] = v.w;
        } else {                             // i contiguous (aI==1): float4 along i
            int kk = tid >> 4, iq = tid & 15;
            *(float4*)&As[kk][iq * 4] =
                *(const float4*)(A + (ll)(k0 + kk) * aK + (i0 + iq * 4));
        }
        if (bJ == 1) {                       // j contiguous: float4 along j
            int kk = tid >> 4, jq = tid & 15;
            *(float4*)&Bs[kk][jq * 4] =
                *(const float4*)(B + (ll)(k0 + kk) * bK + (j0 + jq * 4));
        } else {                             // k contiguous (bK==1): float4 along k, transpose
            int j = tid >> 2, kq = tid & 3;
            float4 v = *(const float4*)(B + (ll)(j0 + j) * bJ + (k0 + kq * 4));
            Bs[kq * 4 + 0][j] = v.x; Bs[kq * 4 + 1][j] = v.y;
            Bs[kq * 4 + 2][j] = v.z; Bs[kq * 4 + 3][j] = v.w;
        }
        __syncthreads();
        #pragma unroll
        for (int kk = 0; kk < 16; ++kk) {
            float4 a4 = *(float4*)&As[kk][ty * 4];
            float4 b4 = *(float4*)&Bs[kk][tx * 4];
            float a[4] = {a4.x, a4.y, a4.z, a4.w};
            float bb[4] = {b4.x, b4.y, b4.z, b4.w};
            #pragma unroll
            for (int m = 0; m < 4; ++m)
                #pragma unroll
                for (int n = 0; n < 4; ++n)
                    acc[m][n] = fmaf(a[m], bb[n], acc[m][n]);
        }
        __syncthreads();
    }

    #pragma unroll
    for (int m = 0; m < 4; ++m) {
        int gi = i0 + ty * 4 + m;
        ll ro = (ll)gi * N + j0 + tx * 4;
        float v[4];
        #pragma unroll
        for (int n = 0; n < 4; ++n) v[n] = alpha * acc[m][n];
        if (cinMode >= 1) {
            float4 ci = *(const float4*)(Cin + ro);
            v[0] += ci.x; v[1] += ci.y; v[2] += ci.z; v[3] += ci.w;
        }
        if (cinMode == 2) {
            #pragma unroll
            for (int n = 0; n < 4; ++n) v[n] += Cin[(ll)(j0 + tx * 4 + n) * N + gi];
        }
        if (accum) {
            float4 co = *(const float4*)(C + ro);
            v[0] += co.x; v[1] += co.y; v[2] += co.z; v[3] += co.w;
        }
        float4 o; o.x = v[0]; o.y = v[1]; o.z = v[2]; o.w = v[3];
        *(float4*)(C + ro) = o;
    }
}

// ---------------------------------------------------------------------------
// Gram partials: part[p][b][t] = X[b][i0:i0+64, kchunk] . X[b][j0:j0+64, kchunk]^T
// over k in [0,2047). Upper-triangle tiles only (t -> (ti,tj), ti<=tj), P=8
// K-chunks of 256. Grid 1920 blocks (XCD-chunk swizzled).
// ---------------------------------------------------------------------------
__global__ __launch_bounds__(256) void gram_part_k(const float* __restrict__ x,
                                                   float* __restrict__ part)
{
    int flat = blockIdx.x;                      // 0..1919
    int swz = (flat & 7) * 240 + (flat >> 3);   // 1920/8=240 per XCD chunk
    int b = swz / 120;
    int rr = swz % 120;
    int p = rr / 15, t = rr % 15;
    int ti = 0, rem = t;
    while (rem >= 5 - ti) { rem -= 5 - ti; ++ti; }
    int tj = ti + rem;
    int i0 = ti * 64, j0 = tj * 64;
    const float* X = x + (ll)b * 320 * 2048;
    __shared__ float As[16][68], Bs[16][68];
    int tid = threadIdx.x;
    int f = tid >> 2, kq = tid & 3;
    int tx = tid & 15, ty = tid >> 4;
    float acc[4][4] = {};
    int k0base = p * 256;

    for (int it = 0; it < 16; ++it) {
        int kg = k0base + it * 16 + kq * 4;
        float4 va = *(const float4*)(X + (ll)(i0 + f) * 2048 + kg);
        float4 vb = *(const float4*)(X + (ll)(j0 + f) * 2048 + kg);
        if (kg + 3 >= 2047) {                   // mask k==2047 (last context col excl.)
            float* pa = &va.x; float* pb = &vb.x;
            #pragma unroll
            for (int u = 0; u < 4; ++u)
                if (kg + u >= 2047) { pa[u] = 0.f; pb[u] = 0.f; }
        }
        As[kq * 4 + 0][f] = va.x; As[kq * 4 + 1][f] = va.y;
        As[kq * 4 + 2][f] = va.z; As[kq * 4 + 3][f] = va.w;
        Bs[kq * 4 + 0][f] = vb.x; Bs[kq * 4 + 1][f] = vb.y;
        Bs[kq * 4 + 2][f] = vb.z; Bs[kq * 4 + 3][f] = vb.w;
        __syncthreads();
        #pragma unroll
        for (int kk = 0; kk < 16; ++kk) {
            float4 a4 = *(float4*)&As[kk][ty * 4];
            float4 b4 = *(float4*)&Bs[kk][tx * 4];
            float a[4] = {a4.x, a4.y, a4.z, a4.w};
            float bb[4] = {b4.x, b4.y, b4.z, b4.w};
            #pragma unroll
            for (int m = 0; m < 4; ++m)
                #pragma unroll
                for (int n = 0; n < 4; ++n)
                    acc[m][n] = fmaf(a[m], bb[n], acc[m][n]);
        }
        __syncthreads();
    }
    float* out = part + (((ll)p * 16 + b) * 15 + t) * 4096;
    #pragma unroll
    for (int m = 0; m < 4; ++m) {
        float4 o; o.x = acc[m][0]; o.y = acc[m][1]; o.z = acc[m][2]; o.w = acc[m][3];
        *(float4*)(out + (ty * 4 + m) * 64 + tx * 4) = o;
    }
}

// Sum 8 partials per tile, write both triangles of Gx. Grid 240 = 16*15.
__global__ __launch_bounds__(256) void gram_red_k(const float* __restrict__ part,
                                                  float* __restrict__ Gx)
{
    int bt = blockIdx.x;
    int b = bt / 15, t = bt % 15;
    int ti = 0, rem = t;
    while (rem >= 5 - ti) { rem -= 5 - ti; ++ti; }
    int tj = ti + rem;
    int i0 = ti * 64, j0 = tj * 64;
    int tid = threadIdx.x;
    int tx = tid & 15, rg = tid >> 4;
    float* Gb = Gx + (ll)b * 102400;
    #pragma unroll
    for (int m = 0; m < 4; ++m) {
        int r = rg * 4 + m;
        float s[4] = {};
        for (int p = 0; p < 8; ++p) {
            const float* src = part + (((ll)p * 16 + b) * 15 + t) * 4096 + r * 64 + tx * 4;
            float4 v = *(const float4*)src;
            s[0] += v.x; s[1] += v.y; s[2] += v.z; s[3] += v.w;
        }
        float4 o; o.x = s[0]; o.y = s[1]; o.z = s[2]; o.w = s[3];
        *(float4*)(Gb + (ll)(i0 + r) * 320 + j0 + tx * 4) = o;
        #pragma unroll
        for (int u = 0; u < 4; ++u)
            Gb[(ll)(j0 + tx * 4 + u) * 320 + (i0 + r)] = s[u];
    }
}

// W = blockdiag(I64, emb(128x128), I128)  -> (320 x 320)
__global__ void build_W_k(const float* __restrict__ emb, float* __restrict__ W)
{
    int idx = blockIdx.x * 256 + threadIdx.x;
    if (idx >= 320 * 320) return;
    int i = idx / 320, j = idx % 320;
    float v = 0.f;
    if (i < 64) v = (i == j) ? 1.f : 0.f;
    else if (i < 192) v = (j >= 64 && j < 192) ? emb[(i - 64) * 128 + (j - 64)] : 0.f;
    else v = (j == i) ? 1.f : 0.f;
    W[idx] = v;
}

// r0[b][c][i] = emb[i-192][c] for i in [192,320), else 0.  (16 x 128 x 320)
__global__ void init_r_k(const float* __restrict__ emb, float* __restrict__ r)
{
    int idx = blockIdx.x * 256 + threadIdx.x;
    if (idx >= 16 * 128 * 320) return;
    int i = idx % 320;
    int c = (idx / 320) % 128;
    r[idx] = (i >= 192) ? emb[(i - 192) * 128 + c] : 0.f;
}

// ---------------------------------------------------------------------------
// Fused logits + softmax. Per block: 64 n-rows x 128 cats, K=320.
// logits[b][n][c] = sum_f x[b][f][n] * LW[b][c*320+f]; pred = softmax rows.
// Grid (32, 16). 256 threads, acc 8x4 per thread.
// ---------------------------------------------------------------------------
__global__ __launch_bounds__(256) void logits_sm_k(const float* __restrict__ x,
                                                   const float* __restrict__ LW,
                                                   float* __restrict__ logits,
                                                   float* __restrict__ pred)
{
    int b = blockIdx.y;
    int i0 = blockIdx.x * 64;
    const float* X = x + (ll)b * 320 * 2048;
    const float* Lb = LW + (ll)b * 128 * 320;
    __shared__ float As[16][68];    // [k][n]
    __shared__ float Bs[16][132];   // [k][c]
    int tid = threadIdx.x;
    int tx = tid & 31, ty = tid >> 5;     // c-group 0..31, n-group 0..7
    float acc[8][4] = {};

    for (int k0 = 0; k0 < 320; k0 += 16) {
        {   // A: n contiguous
            int kk = tid >> 4, nq = tid & 15;
            *(float4*)&As[kk][nq * 4] =
                *(const float4*)(X + (ll)(k0 + kk) * 2048 + i0 + nq * 4);
        }
        {   // B: f contiguous per category row -> transpose into LDS
            #pragma unroll
            for (int s = 0; s < 2; ++s) {
                int idx = s * 256 + tid;          // 0..511
                int c = idx >> 2, kq = idx & 3;
                float4 v = *(const float4*)(Lb + (ll)c * 320 + k0 + kq * 4);
                Bs[kq * 4 + 0][c] = v.x; Bs[kq * 4 + 1][c] = v.y;
                Bs[kq * 4 + 2][c] = v.z; Bs[kq * 4 + 3][c] = v.w;
            }
        }
        __syncthreads();
        #pragma unroll
        for (int kk = 0; kk < 16; ++kk) {
            float4 a0 = *(float4*)&As[kk][ty * 8];
            float4 a1 = *(float4*)&As[kk][ty * 8 + 4];
            float4 b4 = *(float4*)&Bs[kk][tx * 4];
            float a[8] = {a0.x, a0.y, a0.z, a0.w, a1.x, a1.y, a1.z, a1.w};
            float bb[4] = {b4.x, b4.y, b4.z, b4.w};
            #pragma unroll
            for (int m = 0; m < 8; ++m)
                #pragma unroll
                for (int n = 0; n < 4; ++n)
                    acc[m][n] = fmaf(a[m], bb[n], acc[m][n]);
        }
        __syncthreads();
    }

    // softmax across 128 cats = 32 lanes x 4 each; rows live in half-waves.
    #pragma unroll
    for (int m = 0; m < 8; ++m) {
        int n_glob = i0 + ty * 8 + m;
        ll ro = ((ll)b * 2048 + n_glob) * 128 + tx * 4;
        float v0 = acc[m][0], v1 = acc[m][1], v2 = acc[m][2], v3 = acc[m][3];
        float mx = fmaxf(fmaxf(v0, v1), fmaxf(v2, v3));
        #pragma unroll
        for (int off = 16; off; off >>= 1) mx = fmaxf(mx, __shfl_xor(mx, off));
        float e0 = expf(v0 - mx), e1 = expf(v1 - mx);
        float e2 = expf(v2 - mx), e3 = expf(v3 - mx);
        float sm = e0 + e1 + e2 + e3;
        #pragma unroll
        for (int off = 16; off; off >>= 1) sm += __shfl_xor(sm, off);
        float inv = 1.f / sm;
        float4 lo; lo.x = v0; lo.y = v1; lo.z = v2; lo.w = v3;
        float4 po; po.x = e0 * inv; po.y = e1 * inv; po.z = e2 * inv; po.w = e3 * inv;
        *(float4*)(logits + ro) = lo;
        *(float4*)(pred + ro) = po;
    }
}

extern "C" void kernel_launch(void* const* d_in, const int* in_sizes, int n_in,
                              void* d_out, int out_size, void* d_ws, size_t ws_size,
                              hipStream_t stream)
{
    const float* x   = (const float*)d_in[0];  // (16, 320, 2048)
    const float* emb = (const float*)d_in[1];  // (128, 128)
    const float* Wq  = (const float*)d_in[2];  // (3,1,320,320)
    const float* Wk  = (const float*)d_in[3];
    const float* Wv  = (const float*)d_in[4];
    const float* P   = (const float*)d_in[5];

    float* logits = (float*)d_out;                    // (16, 2048, 128)
    float* pred   = logits + (ll)16 * 2048 * 128;

    const ll SZ = 320 * 320;
    const ll RS = (ll)128 * 320;
    float* ws = (float*)d_ws;
    float* W   = ws;  ws += SZ;
    float* Gx  = ws;  ws += 16 * SZ;
    float* T1  = ws;  ws += 16 * SZ;
    float* G   = ws;  ws += 16 * SZ;
    float* PV  = ws;  ws += 3 * SZ;
    float* KQ  = ws;  ws += 3 * SZ;
    float* Al  = ws;  ws += 48 * SZ;   // 3 layers x 16 batches
    float* U   = ws;  ws += 16 * SZ;
    float* V   = ws;  ws += 16 * SZ;   // (V region only used as part of 'part' alias)
    float* r0  = ws;  ws += 16 * RS;
    float* r1  = ws;  ws += 16 * RS;
    float* LW  = ws;  ws += 16 * RS;
    float* part = Al;                  // 8*16*15*4096 = 7.86M floats <= Al+U+V (8.19M)

    auto gemm = [&](const float* A, ll aB, ll aI, ll aK,
                    const float* B, ll bB, ll bK, ll bJ,
                    const float* Cin, ll ciB, int cinMode,
                    float* C, ll cB, int accum,
                    int M, int N, int K, int batch, float alpha) {
        dim3 g(N / 64, M / 64, batch);
        gemm_k<<<g, 256, 0, stream>>>(A, aB, aI, aK, B, bB, bK, bJ,
                                      Cin, ciB, cinMode, C, cB, accum, M, N, K, alpha);
    };

    // 1) W = blockdiag(I64, emb, I128)
    build_W_k<<<400, 256, 0, stream>>>(emb, W);

    // 2) Gram of x context cols: Gx[b] = x[:, :2047] x[:, :2047]^T
    gram_part_k<<<1920, 256, 0, stream>>>(x, part);
    gram_red_k<<<240, 256, 0, stream>>>(part, Gx);

    // 3) G = W Gx W^T
    gemm(W, 0, 320, 1,  Gx, SZ, 320, 1,  nullptr, 0, 0,  T1, SZ, 0, 320, 320, 320, 16, 1.f);
    gemm(T1, SZ, 320, 1,  W, 0, 1, 320,  nullptr, 0, 0,  G,  SZ, 0, 320, 320, 320, 16, 1.f);

    // 4) PV_l = P_l Wv_l ; KQ_l = Wk_l^T Wq_l
    gemm(P,  SZ, 320, 1,  Wv, SZ, 320, 1,  nullptr, 0, 0,  PV, SZ, 0, 320, 320, 320, 3, 1.f);
    gemm(Wk, SZ, 1, 320,  Wq, SZ, 320, 1,  nullptr, 0, 0,  KQ, SZ, 0, 320, 320, 320, 3, 1.f);

    // 5) layers: A_l = (1/2047) PV_l (G KQ_l);  G += U + U^T + U A^T, U = A G
    for (int l = 0; l < 3; ++l) {
        float* Acur = Al + (ll)l * 16 * SZ;
        gemm(G, SZ, 320, 1,  KQ + (ll)l * SZ, 0, 320, 1,  nullptr, 0, 0,
             T1, SZ, 0, 320, 320, 320, 16, 1.f);
        gemm(PV + (ll)l * SZ, 0, 320, 1,  T1, SZ, 320, 1,  nullptr, 0, 0,
             Acur, SZ, 0, 320, 320, 320, 16, 1.f / 2047.f);
        if (l < 2) {
            gemm(Acur, SZ, 320, 1,  G, SZ, 320, 1,  nullptr, 0, 0,
                 U, SZ, 0, 320, 320, 320, 16, 1.f);
            // G += U Acur^T + U + U^T   (fused gupd)
            gemm(U, SZ, 320, 1,  Acur, SZ, 1, 320,  U, SZ, 2,
                 G, SZ, 1, 320, 320, 320, 16, 1.f);
        }
    }

    // 6) r chain: r <- r (I + A_l), l = 2,1,0; LW = r W
    init_r_k<<<2560, 256, 0, stream>>>(emb, r0);
    // r1 = r0 + E^T A2[192:,:]  (K=128 via structure of r0)
    gemm(emb, 0, 1, 128,  Al + (ll)2 * 16 * SZ + 192 * 320, SZ, 320, 1,  r0, RS, 1,
         r1, RS, 0, 128, 320, 128, 16, 1.f);
    gemm(r1, RS, 320, 1,  Al + (ll)1 * 16 * SZ, SZ, 320, 1,  r1, RS, 1,
         r0, RS, 0, 128, 320, 320, 16, 1.f);
    gemm(r0, RS, 320, 1,  Al, SZ, 320, 1,  r0, RS, 1,
         r1, RS, 0, 128, 320, 320, 16, 1.f);
    gemm(r1, RS, 320, 1,  W, 0, 320, 1,  nullptr, 0, 0,
         LW, RS, 0, 128, 320, 320, 16, 1.f);

    // 7) logits + softmax fused
    logits_sm_k<<<dim3(32, 16), 256, 0, stream>>>(x, LW, logits, pred);
}